// Round 14
// baseline (115.367 us; speedup 1.0000x reference)
//
#include <hip/hip_runtime.h>

#define EPSF 1e-8f

typedef __fp16   h2v   __attribute__((ext_vector_type(2)));
typedef _Float16 half8 __attribute__((ext_vector_type(8)));
typedef float    f32x4  __attribute__((ext_vector_type(4)));
typedef float    f32x16 __attribute__((ext_vector_type(16)));

constexpr int Bn = 64, Cc = 768, Nn = 1024, Mm = 100;

__device__ inline f32x4 zero4() { f32x4 z; z[0]=z[1]=z[2]=z[3]=0.f; return z; }
__device__ inline f32x16 zero16() {
    f32x16 z;
#pragma unroll
    for (int i = 0; i < 16; ++i) z[i] = 0.f;
    return z;
}

union U4H8 { uint4 u; half8 h; h2v p[4]; };

__device__ inline unsigned pkr(float a, float b) {
    union { h2v p; unsigned u; } cv;
    cv.p = __builtin_amdgcn_cvt_pkrtz(a, b);
    return cv.u;
}

// async global->LDS, 16 B per lane: LDS dest = wave-uniform base + lane*16.
__device__ inline void gload_lds16(const void* g, void* s) {
    __builtin_amdgcn_global_load_lds(
        (const __attribute__((address_space(1))) unsigned int*)g,
        (__attribute__((address_space(3))) unsigned int*)s, 16, 0, 0);
}

// Prep.
// GEMM1 A (normalized mem, 16x16x32 frag-major, hi/lo interleaved):
//   1KB-slot g = (s*7 + t)*2 + hilo   (s = c>>5 K-step, t = m>>4 tile)
//   mF[(g*64 + kg*16 + ml)*8 + j]     (kg = (c>>3)&3, j = c&7, ml = m&15)
//   m padded to 112 (rows >=100 zero).
// GEMM2 A (raw mem, 32x32x16 frag-major, unchanged):
//   muF[((ct*8+ms)*64 + hm*32 + cl)*8 + jm]
__global__ __launch_bounds__(256) void prep_kernel(const float* __restrict__ mem,
                                                   _Float16* __restrict__ mF,
                                                   _Float16* __restrict__ muF) {
    int m = blockIdx.x, t = threadIdx.x;
    float inv = 0.f;
    if (m < Mm) {
        float ss = 0.f;
        for (int c = t; c < Cc; c += 256) { float v = mem[m * Cc + c]; ss += v * v; }
        __shared__ float red[256];
        red[t] = ss; __syncthreads();
        for (int s = 128; s > 0; s >>= 1) { if (t < s) red[t] += red[t + s]; __syncthreads(); }
        inv = 1.f / fmaxf(sqrtf(red[0]), 1e-12f);
    }
    for (int c = t; c < Cc; c += 256) {
        float v = (m < Mm) ? mem[m * Cc + c] : 0.f;
        float nv = v * inv;
        _Float16 hh = (_Float16)nv;
        _Float16 ll = (_Float16)(nv - (float)hh);
        if (m < 112) {
            int s = c >> 5, kg = (c >> 3) & 3, j = c & 7, tt = m >> 4, ml = m & 15;
            size_t g = (size_t)(s * 7 + tt) * 2;
            mF[((g + 0) * 64 + kg * 16 + ml) * 8 + j] = hh;
            mF[((g + 1) * 64 + kg * 16 + ml) * 8 + j] = ll;
        }
        int ct = c >> 5, cl = c & 31, ms = m >> 4, hm = (m >> 3) & 1, jm = m & 7;
        muF[((size_t)(ct * 8 + ms) * 64 + hm * 32 + cl) * 8 + jm] = (_Float16)v;
    }
}

// Kernel A: 16x16x32 MFMA, one wave per 16-px group -> 4096 waves. Block =
// 8 waves (512 thr), LDS 56KB -> 2 blocks/CU -> 4 waves/SIMD (2x round 13).
// Round = 2 K-32 steps; fragments LDS-staged per block; counted-vmcnt barrier.
__global__ __launch_bounds__(512, 4) void score_kernel(
    const float* __restrict__ z, const _Float16* __restrict__ mF,
    float* __restrict__ attn_out) {
    __shared__ uint4 fbuf[2][28][64];  // [buf][slot = p*14 + t*2 + hilo][lane] 56 KB

    const int tid = threadIdx.x;
    const int w = tid >> 6;            // 0..7
    const int l = tid & 63;
    const int wid = (blockIdx.x << 3) | w;  // 0..4095, one 16-px group each
    const int b = wid >> 6;
    const int pxb = (wid & 63) * 16;
    const int px = l & 15;
    const int kg = l >> 4;             // k-group 0..3
    const float* zr = z + (size_t)b * Cc * Nn + pxb + px + (size_t)kg * 8 * Nn;
    const uint4* mf4 = (const uint4*)mF;
    // staging split: waves 0..3 stage 4 slots, waves 4..7 stage 3 slots (28 total)
    const int nslot = (w < 4) ? 4 : 3;
    const int q0 = (w < 4) ? (w * 4) : (16 + (w - 4) * 3);

    f32x4 acc[7];
#pragma unroll
    for (int t = 0; t < 7; ++t) acc[t] = zero4();
    float ss = 0.f;
    float zA[2][8], zB[2][8];

    // prologue: stage round 0 (own slots), then z round 0; wait staging only.
#pragma unroll
    for (int i = 0; i < 4; ++i)
        if (i < nslot) gload_lds16(mf4 + (size_t)(q0 + i) * 64 + l, &fbuf[0][q0 + i][0]);
#pragma unroll
    for (int p = 0; p < 2; ++p)
#pragma unroll
        for (int j = 0; j < 8; ++j)
            zA[p][j] = __builtin_nontemporal_load(&zr[(size_t)(p * 32 + j) * Nn]);
    __builtin_amdgcn_sched_barrier(0);
    asm volatile("s_waitcnt vmcnt(16)" ::: "memory");
    __builtin_amdgcn_sched_barrier(0);
    __builtin_amdgcn_s_barrier();
    __builtin_amdgcn_sched_barrier(0);

    // one round: consume ZC + fbuf[FB]; prefetch round R+1 into ZN + fbuf[FB^1]
    auto round_body = [&](int RR, float (&ZC)[2][8], float (&ZN)[2][8], int FB) {
        const bool more = (RR + 1 < 12);
        if (more) {
#pragma unroll
            for (int i = 0; i < 4; ++i)
                if (i < nslot)
                    gload_lds16(mf4 + ((size_t)(RR + 1) * 28 + q0 + i) * 64 + l,
                                &fbuf[FB ^ 1][q0 + i][0]);
#pragma unroll
            for (int p = 0; p < 2; ++p)
#pragma unroll
                for (int j = 0; j < 8; ++j)
                    ZN[p][j] = __builtin_nontemporal_load(
                        &zr[(size_t)(((RR + 1) * 2 + p) * 32 + j) * Nn]);
        }
#pragma unroll
        for (int p = 0; p < 2; ++p) {  // 2 K-32 steps
            U4H8 zh, zl8;
#pragma unroll
            for (int t = 0; t < 4; ++t) {
                float u = ZC[p][2 * t], v = ZC[p][2 * t + 1];
                h2v q = __builtin_amdgcn_cvt_pkrtz(u, v);
                zh.p[t] = q;
                zl8.p[t] = __builtin_amdgcn_cvt_pkrtz(u - (float)q.x, v - (float)q.y);
                ss += u * u + v * v;
            }
#pragma unroll
            for (int t = 0; t < 7; ++t) {
                U4H8 ah, al;
                ah.u = fbuf[FB][p * 14 + t * 2][l];
                al.u = fbuf[FB][p * 14 + t * 2 + 1][l];
                acc[t] = __builtin_amdgcn_mfma_f32_16x16x32_f16(ah.h, zh.h, acc[t], 0, 0, 0);
                acc[t] = __builtin_amdgcn_mfma_f32_16x16x32_f16(al.h, zh.h, acc[t], 0, 0, 0);
                acc[t] = __builtin_amdgcn_mfma_f32_16x16x32_f16(ah.h, zl8.h, acc[t], 0, 0, 0);
            }
        }
        if (more) {
            __builtin_amdgcn_sched_barrier(0);
            asm volatile("s_waitcnt vmcnt(16)" ::: "memory");
            __builtin_amdgcn_sched_barrier(0);
            __builtin_amdgcn_s_barrier();
            __builtin_amdgcn_sched_barrier(0);
        }
    };

#pragma unroll 1
    for (int rp = 0; rp < 6; ++rp) {
        round_body(2 * rp, zA, zB, 0);
        round_body(2 * rp + 1, zB, zA, 1);
    }

    // ---------------- softmax + hard shrinkage (lane: px, kg) ----------------
    // lane (px,kg) holds m = 16t + 4*kg + rr, t=0..6, rr=0..3.
    ss += __shfl_xor(ss, 16);
    ss += __shfl_xor(ss, 32);
    float invn = 1.f / fmaxf(sqrtf(ss), 1e-12f);

    float a_[28];
#pragma unroll
    for (int t = 0; t < 7; ++t)
#pragma unroll
        for (int rr = 0; rr < 4; ++rr) {
            float v = acc[t][rr] * invn;
            if (t == 6 && kg != 0) v = -3.0e38f;  // m >= 100 pad
            a_[t * 4 + rr] = v;
        }
    float mx = -3.0e38f;
#pragma unroll
    for (int r = 0; r < 28; ++r) mx = fmaxf(mx, a_[r]);
    mx = fmaxf(mx, __shfl_xor(mx, 16));
    mx = fmaxf(mx, __shfl_xor(mx, 32));

    float sum = 0.f;
#pragma unroll
    for (int r = 0; r < 28; ++r) { float e = expf(a_[r] - mx); a_[r] = e; sum += e; }
    sum += __shfl_xor(sum, 16);
    sum += __shfl_xor(sum, 32);
    float itot = 1.f / sum;

    float asum = 0.f;
#pragma unroll
    for (int r = 0; r < 28; ++r) {
        float w_ = a_[r] * itot;
        float d = w_ - 0.01f;
        float aa = (d > 0.f) ? (d * w_) / (d + EPSF) : 0.f;
        a_[r] = aa; asum += aa;
    }
    asum += __shfl_xor(asum, 16);
    asum += __shfl_xor(asum, 32);
    float ia = 1.f / (asum + EPSF);
#pragma unroll
    for (int r = 0; r < 28; ++r) a_[r] *= ia;

    // ---- store attn: float4 at m0 = 16t + 4*kg ----
    {
        size_t ob = (size_t)(wid * 16 + px) * (size_t)Mm;
#pragma unroll
        for (int t = 0; t < 7; ++t) {
            if (t < 6 || kg == 0) {
                int m0 = 16 * t + 4 * kg;
                float4 v = make_float4(a_[4 * t], a_[4 * t + 1], a_[4 * t + 2], a_[4 * t + 3]);
                *(float4*)&attn_out[ob + m0] = v;
            }
        }
    }
}

// Kernel B: z_hat = attn @ memory (unchanged from round 13).
__global__ __launch_bounds__(256, 4) void recon_kernel(
    const _Float16* __restrict__ muF, const float* __restrict__ attn_out,
    float* __restrict__ zhat) {
    const int tid = threadIdx.x;
    const int w = tid >> 6;
    const int l = tid & 63;
    const int gb = blockIdx.x;
    const int b = gb >> 5;
    const int pxb = (gb & 31) * 32;
    const int pl = l & 31;
    const int h = l >> 5;

    const float* ap = attn_out + (size_t)(gb * 32 + pl) * (size_t)Mm;
    uint4 bfr[8];
#pragma unroll
    for (int ms = 0; ms < 6; ++ms) {
        float4 fa = *(const float4*)&ap[ms * 16 + h * 8];
        float4 fb = *(const float4*)&ap[ms * 16 + h * 8 + 4];
        bfr[ms] = make_uint4(pkr(fa.x, fa.y), pkr(fa.z, fa.w),
                             pkr(fb.x, fb.y), pkr(fb.z, fb.w));
    }
    {
        float4 fa = (h == 0) ? *(const float4*)&ap[96] : make_float4(0.f, 0.f, 0.f, 0.f);
        bfr[6] = make_uint4(pkr(fa.x, fa.y), pkr(fa.z, fa.w), 0u, 0u);
        bfr[7] = make_uint4(0u, 0u, 0u, 0u);
    }

    const uint4* mu4 = (const uint4*)muF;
    float* zo = zhat + (size_t)b * Cc * Nn + pxb + pl;
    const int ct0 = w * 6;
#pragma unroll 1
    for (int cti = 0; cti < 6; cti += 2) {
        int ct = ct0 + cti;
        f32x16 a2 = zero16(), a3 = zero16();
#pragma unroll
        for (int ms = 0; ms < 7; ++ms) {  // ms=7 has B==0, skipped
            U4H8 A0, A1, Bf;
            A0.u = mu4[(ct * 8 + ms) * 64 + l];
            A1.u = mu4[((ct + 1) * 8 + ms) * 64 + l];
            Bf.u = bfr[ms];
            a2 = __builtin_amdgcn_mfma_f32_32x32x16_f16(A0.h, Bf.h, a2, 0, 0, 0);
            a3 = __builtin_amdgcn_mfma_f32_32x32x16_f16(A1.h, Bf.h, a3, 0, 0, 0);
        }
#pragma unroll
        for (int r = 0; r < 16; ++r) {
            int cl = (r & 3) + 8 * (r >> 2) + 4 * h;
            __builtin_nontemporal_store(a2[r], &zo[(size_t)(ct * 32 + cl) * Nn]);
            __builtin_nontemporal_store(a3[r], &zo[(size_t)(ct * 32 + 32 + cl) * Nn]);
        }
    }
}

extern "C" void kernel_launch(void* const* d_in, const int* in_sizes, int n_in,
                              void* d_out, int out_size, void* d_ws, size_t ws_size,
                              hipStream_t stream) {
    const float* z = (const float*)d_in[0];
    const float* mem = (const float*)d_in[1];
    float* out = (float*)d_out;
    float* zhat = out;                          // 64*768*1024
    float* attn = out + (size_t)Bn * Cc * Nn;   // 64*1024*100
    _Float16* mF = (_Float16*)d_ws;             // 24*7*2*64*8 f16 = 336 KB
    _Float16* muF = mF + 24 * 7 * 2 * 64 * 8;   // 192 KB

    prep_kernel<<<128, 256, 0, stream>>>(mem, mF, muF);
    score_kernel<<<512, 512, 0, stream>>>(z, mF, attn);
    recon_kernel<<<2048, 256, 0, stream>>>(muF, attn, zhat);
}

// Round 15
// 105.706 us; speedup vs baseline: 1.0914x; 1.0914x over previous
//
#include <hip/hip_runtime.h>

#define EPSF 1e-8f

typedef __fp16   h2v   __attribute__((ext_vector_type(2)));
typedef _Float16 half8 __attribute__((ext_vector_type(8)));
typedef float    f32x16 __attribute__((ext_vector_type(16)));

constexpr int Bn = 64, Cc = 768, Nn = 1024, Mm = 100;

__device__ inline f32x16 zero16() {
    f32x16 z;
#pragma unroll
    for (int i = 0; i < 16; ++i) z[i] = 0.f;
    return z;
}

union U4H8 { uint4 u; half8 h; h2v p[4]; };

__device__ inline unsigned pkr(float a, float b) {
    union { h2v p; unsigned u; } cv;
    cv.p = __builtin_amdgcn_cvt_pkrtz(a, b);
    return cv.u;
}

// async global->LDS, 16 B per lane: LDS dest = wave-uniform base + lane*16.
__device__ inline void gload_lds16(const void* g, void* s) {
    __builtin_amdgcn_global_load_lds(
        (const __attribute__((address_space(1))) unsigned int*)g,
        (__attribute__((address_space(3))) unsigned int*)s, 16, 0, 0);
}

// Fragment-major prep (unchanged layouts).
// GEMM1 A (normalized mem, hi/lo f16):  idx = ((cs*4 + mt)*64 + hb*32 + ml)*8 + j
// GEMM2 A (raw mem, transposed):        idx = ((ct*8 + ms)*64 + hm*32 + cl)*8 + jm
__global__ __launch_bounds__(256) void prep_kernel(const float* __restrict__ mem,
                                                   _Float16* __restrict__ mhiF,
                                                   _Float16* __restrict__ mloF,
                                                   _Float16* __restrict__ muF) {
    int m = blockIdx.x, t = threadIdx.x;
    float inv = 0.f;
    if (m < Mm) {
        float ss = 0.f;
        for (int c = t; c < Cc; c += 256) { float v = mem[m * Cc + c]; ss += v * v; }
        __shared__ float red[256];
        red[t] = ss; __syncthreads();
        for (int s = 128; s > 0; s >>= 1) { if (t < s) red[t] += red[t + s]; __syncthreads(); }
        inv = 1.f / fmaxf(sqrtf(red[0]), 1e-12f);
    }
    for (int c = t; c < Cc; c += 256) {
        float v = (m < Mm) ? mem[m * Cc + c] : 0.f;
        float nv = v * inv;
        _Float16 hh = (_Float16)nv;
        _Float16 ll = (_Float16)(nv - (float)hh);
        int cs = c >> 4, hb = (c >> 3) & 1, j = c & 7, mt = m >> 5, ml = m & 31;
        size_t idx = ((size_t)(cs * 4 + mt) * 64 + hb * 32 + ml) * 8 + j;
        mhiF[idx] = hh;
        mloF[idx] = ll;
        int ct = c >> 5, cl = c & 31, ms = m >> 4, hm = (m >> 3) & 1, jm = m & 7;
        size_t idx2 = ((size_t)(ct * 8 + ms) * 64 + hm * 32 + cl) * 8 + jm;
        muF[idx2] = (_Float16)v;
    }
}

// Kernel A: unchanged from round 13 (112 us best-known).
__global__ __launch_bounds__(256) void score_kernel(
    const float* __restrict__ z, const _Float16* __restrict__ mhiF,
    const _Float16* __restrict__ mloF, float* __restrict__ attn_out) {
    __shared__ uint4 fbuf[2][4][2][256];  // 64 KB

    const int tid = threadIdx.x;
    const int w = tid >> 6;
    const int l = tid & 63;
    const int wid = (blockIdx.x << 2) | w;  // 0..2047
    const int b = wid >> 5;
    const int pxb = (wid & 31) * 32;
    const int pl = l & 31;
    const int h = l >> 5;
    const float* zr = z + (size_t)b * Cc * Nn + pxb + pl + (size_t)h * 8 * Nn;
    const uint4* mh4 = (const uint4*)mhiF;
    const uint4* ml4 = (const uint4*)mloF;
    const uint4* gh = mh4 + w * 64 + l;
    const uint4* gl = ml4 + w * 64 + l;

    f32x16 acc[4] = {zero16(), zero16(), zero16(), zero16()};
    float ss = 0.f;
    float zbufA[4][8], zbufB[4][8];

#pragma unroll
    for (int i = 0; i < 4; ++i) {
        gload_lds16(gh + i * 256, &fbuf[0][i][0][w * 64]);
        gload_lds16(gl + i * 256, &fbuf[0][i][1][w * 64]);
    }
#pragma unroll
    for (int i = 0; i < 4; ++i)
#pragma unroll
        for (int j = 0; j < 8; ++j)
            zbufA[i][j] = __builtin_nontemporal_load(&zr[(size_t)(i * 16 + j) * Nn]);
    __builtin_amdgcn_sched_barrier(0);
    asm volatile("s_waitcnt vmcnt(32)" ::: "memory");
    __builtin_amdgcn_sched_barrier(0);
    __builtin_amdgcn_s_barrier();
    __builtin_amdgcn_sched_barrier(0);

    auto round_body = [&](int RR, float (&ZC)[4][8], float (&ZN)[4][8], int FB) {
        const bool more = (RR + 1 < 12);
        if (more) {
#pragma unroll
            for (int i = 0; i < 4; ++i) {
                gload_lds16(gh + ((RR + 1) * 4 + i) * 256, &fbuf[FB ^ 1][i][0][w * 64]);
                gload_lds16(gl + ((RR + 1) * 4 + i) * 256, &fbuf[FB ^ 1][i][1][w * 64]);
            }
#pragma unroll
            for (int i = 0; i < 4; ++i)
#pragma unroll
                for (int j = 0; j < 8; ++j)
                    ZN[i][j] = __builtin_nontemporal_load(
                        &zr[(size_t)(((RR + 1) * 4 + i) * 16 + j) * Nn]);
        }
#pragma unroll
        for (int i = 0; i < 4; ++i) {
            U4H8 zh, zl8;
#pragma unroll
            for (int t = 0; t < 4; ++t) {
                float u = ZC[i][2 * t], v = ZC[i][2 * t + 1];
                h2v p = __builtin_amdgcn_cvt_pkrtz(u, v);
                zh.p[t] = p;
                zl8.p[t] = __builtin_amdgcn_cvt_pkrtz(u - (float)p.x, v - (float)p.y);
                ss += u * u + v * v;
            }
            U4H8 ah, al;
#pragma unroll
            for (int mt = 0; mt < 4; ++mt) {
                ah.u = fbuf[FB][i][0][mt * 64 + l];
                al.u = fbuf[FB][i][1][mt * 64 + l];
                acc[mt] = __builtin_amdgcn_mfma_f32_32x32x16_f16(ah.h, zh.h, acc[mt], 0, 0, 0);
                acc[mt] = __builtin_amdgcn_mfma_f32_32x32x16_f16(al.h, zh.h, acc[mt], 0, 0, 0);
                acc[mt] = __builtin_amdgcn_mfma_f32_32x32x16_f16(ah.h, zl8.h, acc[mt], 0, 0, 0);
            }
        }
        if (more) {
            __builtin_amdgcn_sched_barrier(0);
            asm volatile("s_waitcnt vmcnt(32)" ::: "memory");
            __builtin_amdgcn_sched_barrier(0);
            __builtin_amdgcn_s_barrier();
            __builtin_amdgcn_sched_barrier(0);
        }
    };

#pragma unroll 1
    for (int rp = 0; rp < 6; ++rp) {
        round_body(2 * rp, zbufA, zbufB, 0);
        round_body(2 * rp + 1, zbufB, zbufA, 1);
    }

    ss += __shfl_xor(ss, 32);
    float invn = 1.f / fmaxf(sqrtf(ss), 1e-12f);

    float a_[64];
#pragma unroll
    for (int r = 0; r < 64; ++r) {
        int mt = r >> 4, rr = r & 15;
        float v = acc[mt][rr] * invn;
        if (r >= 52) v = -3.0e38f;
        else if (r >= 48) v = (h == 0) ? v : -3.0e38f;
        a_[r] = v;
    }
    float mx = -3.0e38f;
#pragma unroll
    for (int r = 0; r < 52; ++r) mx = fmaxf(mx, a_[r]);
    mx = fmaxf(mx, __shfl_xor(mx, 32));

    float sum = 0.f;
#pragma unroll
    for (int r = 0; r < 52; ++r) { float e = expf(a_[r] - mx); a_[r] = e; sum += e; }
    sum += __shfl_xor(sum, 32);
    float itot = 1.f / sum;

    float asum = 0.f;
#pragma unroll
    for (int r = 0; r < 52; ++r) {
        float w_ = a_[r] * itot;
        float d = w_ - 0.01f;
        float aa = (d > 0.f) ? (d * w_) / (d + EPSF) : 0.f;
        a_[r] = aa; asum += aa;
    }
    asum += __shfl_xor(asum, 32);
    float ia = 1.f / (asum + EPSF);
#pragma unroll
    for (int r = 0; r < 52; ++r) a_[r] *= ia;

    {
        size_t ob = (size_t)(wid * 32 + pl) * (size_t)Mm;
#pragma unroll
        for (int g = 0; g < 13; ++g) {
            int r0 = g * 4;
            int m0 = (r0 >> 4) * 32 + 8 * ((r0 >> 2) & 3) + 4 * h;
            if (g < 12 || h == 0) {
                float4 v = make_float4(a_[r0], a_[r0 + 1], a_[r0 + 2], a_[r0 + 3]);
                *(float4*)&attn_out[ob + m0] = v;
            }
        }
    }
}

// Kernel B: z_hat = attn @ memory. Changes vs round 13:
//  (1) NORMAL stores (L2 writeback aggregates the 128B px-segments of a
//      channel row into full lines; nt dword stores at 4KB stride defeated
//      write-combining).
//  (2) XCD-bijective swizzle: XCD k handles gb in [k*256, k*256+256) ->
//      each XCD's L2 aggregates writes to its own contiguous 24MB of z_hat.
__global__ __launch_bounds__(256, 4) void recon_kernel(
    const _Float16* __restrict__ muF, const float* __restrict__ attn_out,
    float* __restrict__ zhat) {
    const int tid = threadIdx.x;
    const int w = tid >> 6;
    const int l = tid & 63;
    const int orig = blockIdx.x;               // 2048 blocks, 2048%8==0
    const int gb = (orig & 7) * 256 + (orig >> 3);  // bijective XCD swizzle
    const int b = gb >> 5;
    const int pxb = (gb & 31) * 32;
    const int pl = l & 31;
    const int h = l >> 5;

    const float* ap = attn_out + (size_t)(gb * 32 + pl) * (size_t)Mm;
    uint4 bfr[8];
#pragma unroll
    for (int ms = 0; ms < 6; ++ms) {
        float4 fa = *(const float4*)&ap[ms * 16 + h * 8];
        float4 fb = *(const float4*)&ap[ms * 16 + h * 8 + 4];
        bfr[ms] = make_uint4(pkr(fa.x, fa.y), pkr(fa.z, fa.w),
                             pkr(fb.x, fb.y), pkr(fb.z, fb.w));
    }
    {
        float4 fa = (h == 0) ? *(const float4*)&ap[96] : make_float4(0.f, 0.f, 0.f, 0.f);
        bfr[6] = make_uint4(pkr(fa.x, fa.y), pkr(fa.z, fa.w), 0u, 0u);
        bfr[7] = make_uint4(0u, 0u, 0u, 0u);
    }

    const uint4* mu4 = (const uint4*)muF;
    float* zo = zhat + (size_t)b * Cc * Nn + pxb + pl;
    const int ct0 = w * 6;
#pragma unroll 1
    for (int cti = 0; cti < 6; cti += 2) {
        int ct = ct0 + cti;
        f32x16 a2 = zero16(), a3 = zero16();
#pragma unroll
        for (int ms = 0; ms < 7; ++ms) {  // ms=7 has B==0, skipped
            U4H8 A0, A1, Bf;
            A0.u = mu4[(ct * 8 + ms) * 64 + l];
            A1.u = mu4[((ct + 1) * 8 + ms) * 64 + l];
            Bf.u = bfr[ms];
            a2 = __builtin_amdgcn_mfma_f32_32x32x16_f16(A0.h, Bf.h, a2, 0, 0, 0);
            a3 = __builtin_amdgcn_mfma_f32_32x32x16_f16(A1.h, Bf.h, a3, 0, 0, 0);
        }
#pragma unroll
        for (int r = 0; r < 16; ++r) {
            int cl = (r & 3) + 8 * (r >> 2) + 4 * h;
            zo[(size_t)(ct * 32 + cl) * Nn] = a2[r];
            zo[(size_t)(ct * 32 + 32 + cl) * Nn] = a3[r];
        }
    }
}

extern "C" void kernel_launch(void* const* d_in, const int* in_sizes, int n_in,
                              void* d_out, int out_size, void* d_ws, size_t ws_size,
                              hipStream_t stream) {
    const float* z = (const float*)d_in[0];
    const float* mem = (const float*)d_in[1];
    float* out = (float*)d_out;
    float* zhat = out;                          // 64*768*1024
    float* attn = out + (size_t)Bn * Cc * Nn;   // 64*1024*100
    _Float16* mhiF = (_Float16*)d_ws;           // 192 KB
    _Float16* mloF = mhiF + 48 * 4 * 64 * 8;    // 192 KB
    _Float16* muF = mloF + 48 * 4 * 64 * 8;     // 192 KB

    prep_kernel<<<128, 256, 0, stream>>>(mem, mhiF, mloF, muF);
    score_kernel<<<512, 256, 0, stream>>>(z, mhiF, mloF, attn);
    recon_kernel<<<2048, 256, 0, stream>>>(muF, attn, zhat);
}

// Round 16
// 94.849 us; speedup vs baseline: 1.2163x; 1.1145x over previous
//
#include <hip/hip_runtime.h>

#define EPSF 1e-8f

typedef __fp16   h2v   __attribute__((ext_vector_type(2)));
typedef _Float16 half8 __attribute__((ext_vector_type(8)));
typedef float    f32x16 __attribute__((ext_vector_type(16)));

constexpr int Bn = 64, Cc = 768, Nn = 1024, Mm = 100;

__device__ inline f32x16 zero16() {
    f32x16 z;
#pragma unroll
    for (int i = 0; i < 16; ++i) z[i] = 0.f;
    return z;
}

union U4H8 { uint4 u; half8 h; h2v p[4]; };

__device__ inline unsigned pkr(float a, float b) {
    union { h2v p; unsigned u; } cv;
    cv.p = __builtin_amdgcn_cvt_pkrtz(a, b);
    return cv.u;
}

// async global->LDS, 16 B per lane: LDS dest = wave-uniform base + lane*16.
__device__ inline void gload_lds16(const void* g, void* s) {
    __builtin_amdgcn_global_load_lds(
        (const __attribute__((address_space(1))) unsigned int*)g,
        (__attribute__((address_space(3))) unsigned int*)s, 16, 0, 0);
}

// Fragment-major prep (unchanged layouts).
// GEMM1 A (normalized mem, hi/lo f16):  idx = ((cs*4 + mt)*64 + hb*32 + ml)*8 + j
// GEMM2 A (raw mem, transposed):        idx = ((ct*8 + ms)*64 + hm*32 + cl)*8 + jm
__global__ __launch_bounds__(256) void prep_kernel(const float* __restrict__ mem,
                                                   _Float16* __restrict__ mhiF,
                                                   _Float16* __restrict__ mloF,
                                                   _Float16* __restrict__ muF) {
    int m = blockIdx.x, t = threadIdx.x;
    float inv = 0.f;
    if (m < Mm) {
        float ss = 0.f;
        for (int c = t; c < Cc; c += 256) { float v = mem[m * Cc + c]; ss += v * v; }
        __shared__ float red[256];
        red[t] = ss; __syncthreads();
        for (int s = 128; s > 0; s >>= 1) { if (t < s) red[t] += red[t + s]; __syncthreads(); }
        inv = 1.f / fmaxf(sqrtf(red[0]), 1e-12f);
    }
    for (int c = t; c < Cc; c += 256) {
        float v = (m < Mm) ? mem[m * Cc + c] : 0.f;
        float nv = v * inv;
        _Float16 hh = (_Float16)nv;
        _Float16 ll = (_Float16)(nv - (float)hh);
        int cs = c >> 4, hb = (c >> 3) & 1, j = c & 7, mt = m >> 5, ml = m & 31;
        size_t idx = ((size_t)(cs * 4 + mt) * 64 + hb * 32 + ml) * 8 + j;
        mhiF[idx] = hh;
        mloF[idx] = ll;
        int ct = c >> 5, cl = c & 31, ms = m >> 4, hm = (m >> 3) & 1, jm = m & 7;
        size_t idx2 = ((size_t)(ct * 8 + ms) * 64 + hm * 32 + cl) * 8 + jm;
        muF[idx2] = (_Float16)v;
    }
}

// Fused kernel: round-15 score (LDS-staged frags, counted-vmcnt barriers) +
// in-register bfr build (round-4 verified) + round-15 recon (normal stores),
// all per wave for its own 32-px group. No attn re-read, no second launch,
// and block drift lets z-reads and z_hat-writes overlap across blocks.
__global__ __launch_bounds__(256) void fused_kernel(
    const float* __restrict__ z, const _Float16* __restrict__ mhiF,
    const _Float16* __restrict__ mloF, const _Float16* __restrict__ muF,
    float* __restrict__ zhat, float* __restrict__ attn_out) {
    __shared__ uint4 fbuf[2][4][2][256];  // 64 KB (phase 1 only)

    const int tid = threadIdx.x;
    const int w = tid >> 6;
    const int l = tid & 63;
    const int orig = blockIdx.x;                    // 512 blocks, 512%8==0
    const int gbblk = (orig & 7) * 64 + (orig >> 3);  // bijective XCD swizzle
    const int wid = (gbblk << 2) | w;               // 0..2047
    const int b = wid >> 5;
    const int pxb = (wid & 31) * 32;
    const int pl = l & 31;
    const int h = l >> 5;
    const float* zr = z + (size_t)b * Cc * Nn + pxb + pl + (size_t)h * 8 * Nn;
    const uint4* mh4 = (const uint4*)mhiF;
    const uint4* ml4 = (const uint4*)mloF;
    const uint4* gh = mh4 + w * 64 + l;
    const uint4* gl = ml4 + w * 64 + l;

    f32x16 acc[4] = {zero16(), zero16(), zero16(), zero16()};
    float ss = 0.f;
    float zbufA[4][8], zbufB[4][8];

#pragma unroll
    for (int i = 0; i < 4; ++i) {
        gload_lds16(gh + i * 256, &fbuf[0][i][0][w * 64]);
        gload_lds16(gl + i * 256, &fbuf[0][i][1][w * 64]);
    }
#pragma unroll
    for (int i = 0; i < 4; ++i)
#pragma unroll
        for (int j = 0; j < 8; ++j)
            zbufA[i][j] = __builtin_nontemporal_load(&zr[(size_t)(i * 16 + j) * Nn]);
    __builtin_amdgcn_sched_barrier(0);
    asm volatile("s_waitcnt vmcnt(32)" ::: "memory");
    __builtin_amdgcn_sched_barrier(0);
    __builtin_amdgcn_s_barrier();
    __builtin_amdgcn_sched_barrier(0);

    auto round_body = [&](int RR, float (&ZC)[4][8], float (&ZN)[4][8], int FB) {
        const bool more = (RR + 1 < 12);
        if (more) {
#pragma unroll
            for (int i = 0; i < 4; ++i) {
                gload_lds16(gh + ((RR + 1) * 4 + i) * 256, &fbuf[FB ^ 1][i][0][w * 64]);
                gload_lds16(gl + ((RR + 1) * 4 + i) * 256, &fbuf[FB ^ 1][i][1][w * 64]);
            }
#pragma unroll
            for (int i = 0; i < 4; ++i)
#pragma unroll
                for (int j = 0; j < 8; ++j)
                    ZN[i][j] = __builtin_nontemporal_load(
                        &zr[(size_t)(((RR + 1) * 4 + i) * 16 + j) * Nn]);
        }
#pragma unroll
        for (int i = 0; i < 4; ++i) {
            U4H8 zh, zl8;
#pragma unroll
            for (int t = 0; t < 4; ++t) {
                float u = ZC[i][2 * t], v = ZC[i][2 * t + 1];
                h2v p = __builtin_amdgcn_cvt_pkrtz(u, v);
                zh.p[t] = p;
                zl8.p[t] = __builtin_amdgcn_cvt_pkrtz(u - (float)p.x, v - (float)p.y);
                ss += u * u + v * v;
            }
            U4H8 ah, al;
#pragma unroll
            for (int mt = 0; mt < 4; ++mt) {
                ah.u = fbuf[FB][i][0][mt * 64 + l];
                al.u = fbuf[FB][i][1][mt * 64 + l];
                acc[mt] = __builtin_amdgcn_mfma_f32_32x32x16_f16(ah.h, zh.h, acc[mt], 0, 0, 0);
                acc[mt] = __builtin_amdgcn_mfma_f32_32x32x16_f16(al.h, zh.h, acc[mt], 0, 0, 0);
                acc[mt] = __builtin_amdgcn_mfma_f32_32x32x16_f16(ah.h, zl8.h, acc[mt], 0, 0, 0);
            }
        }
        if (more) {
            __builtin_amdgcn_sched_barrier(0);
            asm volatile("s_waitcnt vmcnt(32)" ::: "memory");
            __builtin_amdgcn_sched_barrier(0);
            __builtin_amdgcn_s_barrier();
            __builtin_amdgcn_sched_barrier(0);
        }
    };

#pragma unroll 1
    for (int rp = 0; rp < 6; ++rp) {
        round_body(2 * rp, zbufA, zbufB, 0);
        round_body(2 * rp + 1, zbufB, zbufA, 1);
    }

    // ---------------- in-register softmax + hard shrinkage ----------------
    ss += __shfl_xor(ss, 32);
    float invn = 1.f / fmaxf(sqrtf(ss), 1e-12f);

    float a_[64];
#pragma unroll
    for (int r = 0; r < 64; ++r) {
        int mt = r >> 4, rr = r & 15;
        float v = acc[mt][rr] * invn;
        if (r >= 52) v = -3.0e38f;
        else if (r >= 48) v = (h == 0) ? v : -3.0e38f;
        a_[r] = v;
    }
    float mx = -3.0e38f;
#pragma unroll
    for (int r = 0; r < 52; ++r) mx = fmaxf(mx, a_[r]);
    mx = fmaxf(mx, __shfl_xor(mx, 32));

    float sum = 0.f;
#pragma unroll
    for (int r = 0; r < 52; ++r) { float e = expf(a_[r] - mx); a_[r] = e; sum += e; }
    sum += __shfl_xor(sum, 32);
    float itot = 1.f / sum;

    float asum = 0.f;
#pragma unroll
    for (int r = 0; r < 52; ++r) {
        float w_ = a_[r] * itot;
        float d = w_ - 0.01f;
        float aa = (d > 0.f) ? (d * w_) / (d + EPSF) : 0.f;
        a_[r] = aa; asum += aa;
    }
    asum += __shfl_xor(asum, 32);
    float ia = 1.f / (asum + EPSF);
#pragma unroll
    for (int r = 0; r < 52; ++r) a_[r] *= ia;
#pragma unroll
    for (int r = 52; r < 64; ++r) a_[r] = 0.f;  // clear -3e38 pads before bfr build

    // ---- store attn ----
    {
        size_t ob = (size_t)(wid * 32 + pl) * (size_t)Mm;
#pragma unroll
        for (int g = 0; g < 13; ++g) {
            int r0 = g * 4;
            int m0 = (r0 >> 4) * 32 + 8 * ((r0 >> 2) & 3) + 4 * h;
            if (g < 12 || h == 0) {
                float4 v = make_float4(a_[r0], a_[r0 + 1], a_[r0 + 2], a_[r0 + 3]);
                *(float4*)&attn_out[ob + m0] = v;
            }
        }
    }

    // ---- build GEMM2 B-fragments in-register (round-4 verified builder) ----
    uint4 bfr[8];
#pragma unroll
    for (int mt = 0; mt < 4; ++mt) {
        unsigned p0 = pkr(a_[16 * mt + 0], a_[16 * mt + 1]);
        unsigned p1 = pkr(a_[16 * mt + 2], a_[16 * mt + 3]);
        unsigned p2 = pkr(a_[16 * mt + 4], a_[16 * mt + 5]);
        unsigned p3 = pkr(a_[16 * mt + 6], a_[16 * mt + 7]);
        unsigned p4 = pkr(a_[16 * mt + 8], a_[16 * mt + 9]);
        unsigned p5 = pkr(a_[16 * mt + 10], a_[16 * mt + 11]);
        unsigned p6 = pkr(a_[16 * mt + 12], a_[16 * mt + 13]);
        unsigned p7 = pkr(a_[16 * mt + 14], a_[16 * mt + 15]);
        unsigned s0 = __shfl_xor(p0, 32), s1 = __shfl_xor(p1, 32);
        unsigned s2 = __shfl_xor(p2, 32), s3 = __shfl_xor(p3, 32);
        unsigned s4 = __shfl_xor(p4, 32), s5 = __shfl_xor(p5, 32);
        unsigned s6 = __shfl_xor(p6, 32), s7 = __shfl_xor(p7, 32);
        bfr[2 * mt]     = h ? make_uint4(s2, s3, p2, p3) : make_uint4(p0, p1, s0, s1);
        bfr[2 * mt + 1] = h ? make_uint4(s6, s7, p6, p7) : make_uint4(p4, p5, s4, s5);
    }

    // ---------------- recon: z_hat = attn @ memory (own 32-px group) ----------------
    const uint4* mu4 = (const uint4*)muF;
    float* zo = zhat + (size_t)b * Cc * Nn + pxb + pl;
#pragma unroll 1
    for (int ct = 0; ct < 24; ct += 2) {
        f32x16 a2 = zero16(), a3 = zero16();
#pragma unroll
        for (int ms = 0; ms < 7; ++ms) {  // ms=7 has B==0, skipped
            U4H8 A0, A1, Bf;
            A0.u = mu4[(ct * 8 + ms) * 64 + l];
            A1.u = mu4[((ct + 1) * 8 + ms) * 64 + l];
            Bf.u = bfr[ms];
            a2 = __builtin_amdgcn_mfma_f32_32x32x16_f16(A0.h, Bf.h, a2, 0, 0, 0);
            a3 = __builtin_amdgcn_mfma_f32_32x32x16_f16(A1.h, Bf.h, a3, 0, 0, 0);
        }
#pragma unroll
        for (int r = 0; r < 16; ++r) {
            int cl = (r & 3) + 8 * (r >> 2) + 4 * h;
            zo[(size_t)(ct * 32 + cl) * Nn] = a2[r];
            zo[(size_t)(ct * 32 + 32 + cl) * Nn] = a3[r];
        }
    }
}

extern "C" void kernel_launch(void* const* d_in, const int* in_sizes, int n_in,
                              void* d_out, int out_size, void* d_ws, size_t ws_size,
                              hipStream_t stream) {
    const float* z = (const float*)d_in[0];
    const float* mem = (const float*)d_in[1];
    float* out = (float*)d_out;
    float* zhat = out;                          // 64*768*1024
    float* attn = out + (size_t)Bn * Cc * Nn;   // 64*1024*100
    _Float16* mhiF = (_Float16*)d_ws;           // 192 KB
    _Float16* mloF = mhiF + 48 * 4 * 64 * 8;    // 192 KB
    _Float16* muF = mloF + 48 * 4 * 64 * 8;     // 192 KB

    prep_kernel<<<128, 256, 0, stream>>>(mem, mhiF, mloF, muF);
    fused_kernel<<<512, 256, 0, stream>>>(z, mhiF, mloF, muF, zhat, attn);
}

// Round 17
// 93.994 us; speedup vs baseline: 1.2274x; 1.0091x over previous
//
#include <hip/hip_runtime.h>

#define EPSF 1e-8f

typedef __fp16   h2v   __attribute__((ext_vector_type(2)));
typedef _Float16 half8 __attribute__((ext_vector_type(8)));
typedef float    f32x16 __attribute__((ext_vector_type(16)));

constexpr int Bn = 64, Cc = 768, Nn = 1024, Mm = 100;

__device__ inline f32x16 zero16() {
    f32x16 z;
#pragma unroll
    for (int i = 0; i < 16; ++i) z[i] = 0.f;
    return z;
}

union U4H8 { uint4 u; half8 h; h2v p[4]; };

__device__ inline unsigned pkr(float a, float b) {
    union { h2v p; unsigned u; } cv;
    cv.p = __builtin_amdgcn_cvt_pkrtz(a, b);
    return cv.u;
}

// async global->LDS, 16 B per lane: LDS dest = wave-uniform base + lane*16.
__device__ inline void gload_lds16(const void* g, void* s) {
    __builtin_amdgcn_global_load_lds(
        (const __attribute__((address_space(1))) unsigned int*)g,
        (__attribute__((address_space(3))) unsigned int*)s, 16, 0, 0);
}

// Fragment-major prep (unchanged layouts).
// GEMM1 A (normalized mem, hi/lo f16):  idx = ((cs*4 + mt)*64 + hb*32 + ml)*8 + j
// GEMM2 A (raw mem, transposed):        idx = ((ct*8 + ms)*64 + hm*32 + cl)*8 + jm
__global__ __launch_bounds__(256) void prep_kernel(const float* __restrict__ mem,
                                                   _Float16* __restrict__ mhiF,
                                                   _Float16* __restrict__ mloF,
                                                   _Float16* __restrict__ muF) {
    int m = blockIdx.x, t = threadIdx.x;
    float inv = 0.f;
    if (m < Mm) {
        float ss = 0.f;
        for (int c = t; c < Cc; c += 256) { float v = mem[m * Cc + c]; ss += v * v; }
        __shared__ float red[256];
        red[t] = ss; __syncthreads();
        for (int s = 128; s > 0; s >>= 1) { if (t < s) red[t] += red[t + s]; __syncthreads(); }
        inv = 1.f / fmaxf(sqrtf(red[0]), 1e-12f);
    }
    for (int c = t; c < Cc; c += 256) {
        float v = (m < Mm) ? mem[m * Cc + c] : 0.f;
        float nv = v * inv;
        _Float16 hh = (_Float16)nv;
        _Float16 ll = (_Float16)(nv - (float)hh);
        int cs = c >> 4, hb = (c >> 3) & 1, j = c & 7, mt = m >> 5, ml = m & 31;
        size_t idx = ((size_t)(cs * 4 + mt) * 64 + hb * 32 + ml) * 8 + j;
        mhiF[idx] = hh;
        mloF[idx] = ll;
        int ct = c >> 5, cl = c & 31, ms = m >> 4, hm = (m >> 3) & 1, jm = m & 7;
        size_t idx2 = ((size_t)(ct * 8 + ms) * 64 + hm * 32 + cl) * 8 + jm;
        muF[idx2] = (_Float16)v;
    }
}

// Fused kernel (round-16 structure). Round-17 changes, recon-only:
//  (1) explicit register double-buffer for A-fragments (cA/nA ping-pong),
//  (2) preload ct={0,1} fragments BEFORE softmax (hide under expf VALU),
//  (3) __launch_bounds__(256,1): phase-2 live set ~180 VGPR; occupancy is
//      grid-capped at 2 blocks/CU (64KB LDS) so the higher cap is free.
__global__ __launch_bounds__(256, 1) void fused_kernel(
    const float* __restrict__ z, const _Float16* __restrict__ mhiF,
    const _Float16* __restrict__ mloF, const _Float16* __restrict__ muF,
    float* __restrict__ zhat, float* __restrict__ attn_out) {
    __shared__ uint4 fbuf[2][4][2][256];  // 64 KB (phase 1 only)

    const int tid = threadIdx.x;
    const int w = tid >> 6;
    const int l = tid & 63;
    const int orig = blockIdx.x;                    // 512 blocks, 512%8==0
    const int gbblk = (orig & 7) * 64 + (orig >> 3);  // bijective XCD swizzle
    const int wid = (gbblk << 2) | w;               // 0..2047
    const int b = wid >> 5;
    const int pxb = (wid & 31) * 32;
    const int pl = l & 31;
    const int h = l >> 5;
    const float* zr = z + (size_t)b * Cc * Nn + pxb + pl + (size_t)h * 8 * Nn;
    const uint4* mh4 = (const uint4*)mhiF;
    const uint4* ml4 = (const uint4*)mloF;
    const uint4* gh = mh4 + w * 64 + l;
    const uint4* gl = ml4 + w * 64 + l;

    f32x16 acc[4] = {zero16(), zero16(), zero16(), zero16()};
    float ss = 0.f;
    float zbufA[4][8], zbufB[4][8];

#pragma unroll
    for (int i = 0; i < 4; ++i) {
        gload_lds16(gh + i * 256, &fbuf[0][i][0][w * 64]);
        gload_lds16(gl + i * 256, &fbuf[0][i][1][w * 64]);
    }
#pragma unroll
    for (int i = 0; i < 4; ++i)
#pragma unroll
        for (int j = 0; j < 8; ++j)
            zbufA[i][j] = __builtin_nontemporal_load(&zr[(size_t)(i * 16 + j) * Nn]);
    __builtin_amdgcn_sched_barrier(0);
    asm volatile("s_waitcnt vmcnt(32)" ::: "memory");
    __builtin_amdgcn_sched_barrier(0);
    __builtin_amdgcn_s_barrier();
    __builtin_amdgcn_sched_barrier(0);

    auto round_body = [&](int RR, float (&ZC)[4][8], float (&ZN)[4][8], int FB) {
        const bool more = (RR + 1 < 12);
        if (more) {
#pragma unroll
            for (int i = 0; i < 4; ++i) {
                gload_lds16(gh + ((RR + 1) * 4 + i) * 256, &fbuf[FB ^ 1][i][0][w * 64]);
                gload_lds16(gl + ((RR + 1) * 4 + i) * 256, &fbuf[FB ^ 1][i][1][w * 64]);
            }
#pragma unroll
            for (int i = 0; i < 4; ++i)
#pragma unroll
                for (int j = 0; j < 8; ++j)
                    ZN[i][j] = __builtin_nontemporal_load(
                        &zr[(size_t)(((RR + 1) * 4 + i) * 16 + j) * Nn]);
        }
#pragma unroll
        for (int i = 0; i < 4; ++i) {
            U4H8 zh, zl8;
#pragma unroll
            for (int t = 0; t < 4; ++t) {
                float u = ZC[i][2 * t], v = ZC[i][2 * t + 1];
                h2v p = __builtin_amdgcn_cvt_pkrtz(u, v);
                zh.p[t] = p;
                zl8.p[t] = __builtin_amdgcn_cvt_pkrtz(u - (float)p.x, v - (float)p.y);
                ss += u * u + v * v;
            }
            U4H8 ah, al;
#pragma unroll
            for (int mt = 0; mt < 4; ++mt) {
                ah.u = fbuf[FB][i][0][mt * 64 + l];
                al.u = fbuf[FB][i][1][mt * 64 + l];
                acc[mt] = __builtin_amdgcn_mfma_f32_32x32x16_f16(ah.h, zh.h, acc[mt], 0, 0, 0);
                acc[mt] = __builtin_amdgcn_mfma_f32_32x32x16_f16(al.h, zh.h, acc[mt], 0, 0, 0);
                acc[mt] = __builtin_amdgcn_mfma_f32_32x32x16_f16(ah.h, zl8.h, acc[mt], 0, 0, 0);
            }
        }
        if (more) {
            __builtin_amdgcn_sched_barrier(0);
            asm volatile("s_waitcnt vmcnt(32)" ::: "memory");
            __builtin_amdgcn_sched_barrier(0);
            __builtin_amdgcn_s_barrier();
            __builtin_amdgcn_sched_barrier(0);
        }
    };

#pragma unroll 1
    for (int rp = 0; rp < 6; ++rp) {
        round_body(2 * rp, zbufA, zbufB, 0);
        round_body(2 * rp + 1, zbufB, zbufA, 1);
    }

    // ---- preload recon ct={0,1} A-fragments (hide under softmax VALU) ----
    const uint4* mu4 = (const uint4*)muF;
    uint4 cA[14], nA[14];
#pragma unroll
    for (int ms = 0; ms < 7; ++ms) {
        cA[ms] = mu4[(0 * 8 + ms) * 64 + l];
        cA[7 + ms] = mu4[(1 * 8 + ms) * 64 + l];
    }

    // ---------------- in-register softmax + hard shrinkage ----------------
    ss += __shfl_xor(ss, 32);
    float invn = 1.f / fmaxf(sqrtf(ss), 1e-12f);

    float a_[64];
#pragma unroll
    for (int r = 0; r < 64; ++r) {
        int mt = r >> 4, rr = r & 15;
        float v = acc[mt][rr] * invn;
        if (r >= 52) v = -3.0e38f;
        else if (r >= 48) v = (h == 0) ? v : -3.0e38f;
        a_[r] = v;
    }
    float mx = -3.0e38f;
#pragma unroll
    for (int r = 0; r < 52; ++r) mx = fmaxf(mx, a_[r]);
    mx = fmaxf(mx, __shfl_xor(mx, 32));

    float sum = 0.f;
#pragma unroll
    for (int r = 0; r < 52; ++r) { float e = expf(a_[r] - mx); a_[r] = e; sum += e; }
    sum += __shfl_xor(sum, 32);
    float itot = 1.f / sum;

    float asum = 0.f;
#pragma unroll
    for (int r = 0; r < 52; ++r) {
        float w_ = a_[r] * itot;
        float d = w_ - 0.01f;
        float aa = (d > 0.f) ? (d * w_) / (d + EPSF) : 0.f;
        a_[r] = aa; asum += aa;
    }
    asum += __shfl_xor(asum, 32);
    float ia = 1.f / (asum + EPSF);
#pragma unroll
    for (int r = 0; r < 52; ++r) a_[r] *= ia;
#pragma unroll
    for (int r = 52; r < 64; ++r) a_[r] = 0.f;  // clear -3e38 pads before bfr build

    // ---- store attn ----
    {
        size_t ob = (size_t)(wid * 32 + pl) * (size_t)Mm;
#pragma unroll
        for (int g = 0; g < 13; ++g) {
            int r0 = g * 4;
            int m0 = (r0 >> 4) * 32 + 8 * ((r0 >> 2) & 3) + 4 * h;
            if (g < 12 || h == 0) {
                float4 v = make_float4(a_[r0], a_[r0 + 1], a_[r0 + 2], a_[r0 + 3]);
                *(float4*)&attn_out[ob + m0] = v;
            }
        }
    }

    // ---- build GEMM2 B-fragments in-register (round-4 verified builder) ----
    uint4 bfr[8];
#pragma unroll
    for (int mt = 0; mt < 4; ++mt) {
        unsigned p0 = pkr(a_[16 * mt + 0], a_[16 * mt + 1]);
        unsigned p1 = pkr(a_[16 * mt + 2], a_[16 * mt + 3]);
        unsigned p2 = pkr(a_[16 * mt + 4], a_[16 * mt + 5]);
        unsigned p3 = pkr(a_[16 * mt + 6], a_[16 * mt + 7]);
        unsigned p4 = pkr(a_[16 * mt + 8], a_[16 * mt + 9]);
        unsigned p5 = pkr(a_[16 * mt + 10], a_[16 * mt + 11]);
        unsigned p6 = pkr(a_[16 * mt + 12], a_[16 * mt + 13]);
        unsigned p7 = pkr(a_[16 * mt + 14], a_[16 * mt + 15]);
        unsigned s0 = __shfl_xor(p0, 32), s1 = __shfl_xor(p1, 32);
        unsigned s2 = __shfl_xor(p2, 32), s3 = __shfl_xor(p3, 32);
        unsigned s4 = __shfl_xor(p4, 32), s5 = __shfl_xor(p5, 32);
        unsigned s6 = __shfl_xor(p6, 32), s7 = __shfl_xor(p7, 32);
        bfr[2 * mt]     = h ? make_uint4(s2, s3, p2, p3) : make_uint4(p0, p1, s0, s1);
        bfr[2 * mt + 1] = h ? make_uint4(s6, s7, p6, p7) : make_uint4(p4, p5, s4, s5);
    }

    // ---------------- recon: z_hat = attn @ memory (reg-dbuf pipeline) ----------------
    float* zo = zhat + (size_t)b * Cc * Nn + pxb + pl;
    auto recon_pair = [&](int ct, uint4 (&CUR)[14], uint4 (&NXT)[14]) {
        if (ct + 2 < 24) {  // prefetch next ct-pair's fragments
#pragma unroll
            for (int ms = 0; ms < 7; ++ms) {
                NXT[ms] = mu4[((ct + 2) * 8 + ms) * 64 + l];
                NXT[7 + ms] = mu4[((ct + 3) * 8 + ms) * 64 + l];
            }
        }
        f32x16 a2 = zero16(), a3 = zero16();
#pragma unroll
        for (int ms = 0; ms < 7; ++ms) {  // ms=7 has B==0, skipped
            U4H8 A0, A1, Bf;
            A0.u = CUR[ms];
            A1.u = CUR[7 + ms];
            Bf.u = bfr[ms];
            a2 = __builtin_amdgcn_mfma_f32_32x32x16_f16(A0.h, Bf.h, a2, 0, 0, 0);
            a3 = __builtin_amdgcn_mfma_f32_32x32x16_f16(A1.h, Bf.h, a3, 0, 0, 0);
        }
#pragma unroll
        for (int r = 0; r < 16; ++r) {
            int cl = (r & 3) + 8 * (r >> 2) + 4 * h;
            zo[(size_t)(ct * 32 + cl) * Nn] = a2[r];
            zo[(size_t)(ct * 32 + 32 + cl) * Nn] = a3[r];
        }
    };
#pragma unroll 1
    for (int cp = 0; cp < 6; ++cp) {
        recon_pair(4 * cp, cA, nA);
        recon_pair(4 * cp + 2, nA, cA);
    }
}

extern "C" void kernel_launch(void* const* d_in, const int* in_sizes, int n_in,
                              void* d_out, int out_size, void* d_ws, size_t ws_size,
                              hipStream_t stream) {
    const float* z = (const float*)d_in[0];
    const float* mem = (const float*)d_in[1];
    float* out = (float*)d_out;
    float* zhat = out;                          // 64*768*1024
    float* attn = out + (size_t)Bn * Cc * Nn;   // 64*1024*100
    _Float16* mhiF = (_Float16*)d_ws;           // 192 KB
    _Float16* mloF = mhiF + 48 * 4 * 64 * 8;    // 192 KB
    _Float16* muF = mloF + 48 * 4 * 64 * 8;     // 192 KB

    prep_kernel<<<128, 256, 0, stream>>>(mem, mhiF, mloF, muF);
    fused_kernel<<<512, 256, 0, stream>>>(z, mhiF, mloF, muF, zhat, attn);
}